// Round 5
// baseline (137.980 us; speedup 1.0000x reference)
//
#include <hip/hip_runtime.h>
#include <string.h>

// Problem constants (from reference setup_inputs)
#define Hh   256
#define SIXH 1536
#define Bb_  32
#define Ll_  512
#define BL_  16384   // B*L
#define Mm_  1024
#define N1_  1024    // 4H
#define K1_  1536    // 6H
#define K2_  1024
#define N2_  256

typedef __attribute__((ext_vector_type(8))) short bf16x8;
typedef __attribute__((ext_vector_type(4))) float f32x4;

__device__ inline float bf2f(unsigned short u){ unsigned x=(unsigned)u<<16; float f; memcpy(&f,&x,4); return f; }
__device__ inline unsigned short f2bf(float f){ unsigned x; memcpy(&x,&f,4); x = x + 0x7FFFu + ((x>>16)&1u); return (unsigned short)(x>>16); }

#define GL16(gp, lp) __builtin_amdgcn_global_load_lds( \
    (const __attribute__((address_space(1))) void*)(gp), \
    (__attribute__((address_space(3))) void*)(lp), 16, 0, 0)

// ---------------------------------------------------------------------------
// Mask dtype detection: flag 0 = int32, 1 = byte(bool), 2 = float32.
__global__ void detect_mask_kernel(const unsigned int* __restrict__ m, int* __restrict__ flag){
  int t = threadIdx.x;
  bool gt1=false, isf=false;
  for (int i=t;i<4096;i+=256){ unsigned v=m[i]; if(v>1u) gt1=true; if(v==0x3F800000u) isf=true; }
  unsigned long long bg = __ballot(gt1), bf = __ballot(isf);
  __shared__ unsigned long long s1[4], s2[4];
  int w = t>>6;
  if ((t&63)==0){ s1[w]=bg; s2[w]=bf; }
  __syncthreads();
  if (t==0){
    bool g = (s1[0]|s1[1]|s1[2]|s1[3])!=0ull;
    bool f = (s2[0]|s2[1]|s2[2]|s2[3])!=0ull;
    *flag = g ? (f?2:1) : 0;
  }
}

// ---------------------------------------------------------------------------
// Tiled transpose + fp32->bf16 convert: W [K][N] f32  ->  Wt [N][K] bf16.
__global__ __launch_bounds__(256) void transpose_conv_kernel(
  const float* __restrict__ W, unsigned short* __restrict__ Wt, int K, int N)
{
  __shared__ float t[32][33];
  int ntx = N >> 5;
  int bx = blockIdx.x % ntx;
  int by = blockIdx.x / ntx;
  int tx = threadIdx.x & 31, ty = threadIdx.x >> 5;
  #pragma unroll
  for (int i=0;i<32;i+=8)
    t[ty+i][tx] = W[(size_t)(by*32+ty+i)*N + bx*32+tx];
  __syncthreads();
  #pragma unroll
  for (int i=0;i<32;i+=8)
    Wt[(size_t)(bx*32+ty+i)*K + by*32+tx] = f2bf(t[tx][ty+i]);
}

// ---------------------------------------------------------------------------
// Gather 6 embedding segments + LayerNorm(1536) -> xn bf16 [16384][1536]
__global__ __launch_bounds__(256) void gather_ln_kernel(
  const int* __restrict__ tok, const int* __restrict__ post,
  const int* __restrict__ auth, const int* __restrict__ act,
  const int* __restrict__ tg,  const int* __restrict__ gidp,
  const float* __restrict__ token_emb, const float* __restrict__ time_emb,
  const float* __restrict__ group_emb,
  const float* __restrict__ ln_g, const float* __restrict__ ln_b,
  unsigned short* __restrict__ xn)
{
  int row = blockIdx.x;
  int t   = threadIdx.x;
  int i0 = tok[row], i1 = post[row], i2 = auth[row], i3 = act[row];
  int i4 = tg[row]; i4 = (i4 < 0) ? 0 : (i4 > 64 ? 64 : i4);
  int i5 = gidp[row];
  float v[6];
  v[0] = token_emb[(size_t)i0*Hh + t];
  v[1] = token_emb[(size_t)i1*Hh + t];
  v[2] = token_emb[(size_t)i2*Hh + t];
  v[3] = token_emb[(size_t)i3*Hh + t];
  v[4] = time_emb[i4*Hh + t];
  v[5] = group_emb[i5*Hh + t];
  float s=0.f, s2=0.f;
  #pragma unroll
  for (int i=0;i<6;i++){ s+=v[i]; s2+=v[i]*v[i]; }
  #pragma unroll
  for (int off=32; off; off>>=1){ s += __shfl_xor(s,off); s2 += __shfl_xor(s2,off); }
  __shared__ float rs[4], rs2[4];
  int w=t>>6;
  if ((t&63)==0){ rs[w]=s; rs2[w]=s2; }
  __syncthreads();
  s  = rs[0]+rs[1]+rs[2]+rs[3];
  s2 = rs2[0]+rs2[1]+rs2[2]+rs2[3];
  float mu   = s * (1.0f/1536.0f);
  float var  = s2 * (1.0f/1536.0f) - mu*mu;
  float rstd = rsqrtf(var + 1e-5f);
  unsigned short* xr = xn + (size_t)row*SIXH;
  #pragma unroll
  for (int i=0;i<6;i++){
    int j = i*Hh + t;
    float y = (v[i]-mu)*rstd*ln_g[j] + ln_b[j];
    xr[j] = f2bf(y);
  }
}

// ---------------------------------------------------------------------------
// GEMM1: 256x256 tile, 8 waves in a 4x2 grid (wave = 64 rows x 128 cols),
// BK=64, 4 phases per K-tile: (B0,k0)->(B1,k0)->(B1,k1)->(B0,k1).
// CROSS-PHASE READ PIPELINING: each phase issues the ds_reads for the NEXT
// phase's MFMA, so the LDS port drains UNDER the current MFMA cluster and the
// next phase's seal is a cheap counted lgkmcnt(4/8/4/0). Only ph1's A/B0
// reads are in-phase (one port-drain stall per K-tile). Fragment live set =
// a0+a1+bP+bQ = 16 x bf16x8 = 64 VGPR (R4-proven no-spill footprint).
// One barrier per phase; one counted vmcnt(6) per K-tile at ph4.
// Staging (2 K-tiles ahead, into verified-dead regions):
//   ph1(X): B0_{X+1} -> slot S^1 (2 GL16)   [B0 of S^1 publishes end-ph4(X-1)]
//   ph4(X): A_{X+2}(4) + B1_{X+2}(2) -> slot S  [publish end-ph3(X)]
// LDS: A slot s at s*16384 elems; B at 32768 + s*16384. 128 KiB.
// Swizzle: 16B granule g of row r stored at g ^ (r&7) (involution, both
// sides; R4-measured 0 bank conflicts with this read pattern).
// A [M][K] bf16, Bt [N][K] bf16, C = silu(A@Bt^T + bias) as bf16 [M][N].
__global__ __launch_bounds__(512, 2) void gemm1_ov_kernel(
  const unsigned short* __restrict__ A, const unsigned short* __restrict__ Bt,
  const float* __restrict__ bias, unsigned short* __restrict__ C,
  int M, int N, int K)
{
  __shared__ unsigned short lds[65536];

  int nbx = N >> 8;
  int bid = blockIdx.x;
  if ((gridDim.x & 7) == 0){                // XCD swizzle (bijective, nwg%8==0)
    int chunk = gridDim.x >> 3;
    bid = (bid & 7)*chunk + (bid >> 3);
  }
  int bx = bid % nbx, by = bid / nbx;
  int brow = by*256, bcol = bx*256;

  int tid = threadIdx.x, lane = tid & 63, wid = tid >> 6;
  int wr = wid >> 1, wc = wid & 1;          // 4 x 2 wave grid

  // ---- staging lane geometry: 64-row GL16 rounds (pre-swizzled global) ----
  int sRow = tid >> 3;                      // 0..63
  int sSw  = ((tid & 7) ^ (sRow & 7)) << 3; // swizzled granule (elements)
  const unsigned short* pA0 = A  + (size_t)(brow +   0 + sRow)*K + sSw;
  const unsigned short* pA1 = A  + (size_t)(brow +  64 + sRow)*K + sSw;
  const unsigned short* pA2 = A  + (size_t)(brow + 128 + sRow)*K + sSw;
  const unsigned short* pA3 = A  + (size_t)(brow + 192 + sRow)*K + sSw;
  const unsigned short* pB0 = Bt + (size_t)(bcol +   0 + sRow)*K + sSw;
  const unsigned short* pB1 = Bt + (size_t)(bcol +  64 + sRow)*K + sSw;
  const unsigned short* pB2 = Bt + (size_t)(bcol + 128 + sRow)*K + sSw;
  const unsigned short* pB3 = Bt + (size_t)(bcol + 192 + sRow)*K + sSw;

  // ---- per-lane fragment read bases (swizzled), in elements ----
  int fr = lane & 15, kb = lane >> 4;
  int g0 = (kb ^ (fr & 3)) | (fr & 4);      // = kb ^ (fr&7); kc=1 -> addr ^32
  int aB = (wr*64  + fr)*64 + g0*8;
  int bB = (wc*128 + fr)*64 + g0*8;

  f32x4 acc[4][8];
  #pragma unroll
  for (int q=0;q<4;q++)
    #pragma unroll
    for (int n=0;n<8;n++) acc[q][n] = (f32x4){0.f,0.f,0.f,0.f};

  bf16x8 a0[4], a1[4], bP[4], bQ[4];        // 16 frags = 64 VGPR

#define ABASE(S) ((S)*16384)
#define BBASE(S) (32768 + (S)*16384)

#define RD_A(buf, S, kc) do{ \
    const unsigned short* L_ = lds + ABASE(S) + (aB ^ ((kc)?32:0)); \
    buf[0] = *(const bf16x8*)(L_); \
    buf[1] = *(const bf16x8*)(L_ + 1024); \
    buf[2] = *(const bf16x8*)(L_ + 2048); \
    buf[3] = *(const bf16x8*)(L_ + 3072); }while(0)

#define RD_B(buf, S, h, kc) do{ \
    const unsigned short* L_ = lds + BBASE(S) + (h)*4096 + (bB ^ ((kc)?32:0)); \
    buf[0] = *(const bf16x8*)(L_); \
    buf[1] = *(const bf16x8*)(L_ + 1024); \
    buf[2] = *(const bf16x8*)(L_ + 2048); \
    buf[3] = *(const bf16x8*)(L_ + 3072); }while(0)

  // one GL16 round = 512 threads x 16B = 64 rows; linear LDS dest.
#define STG(p, DB, OFF) GL16((p) + (OFF), lds + (DB) + wid*512)

#define MMX(AF, BF, NB) do{ \
    __builtin_amdgcn_s_setprio(1); \
    _Pragma("unroll") for (int q=0;q<4;q++) \
      _Pragma("unroll") for (int nn=0;nn<4;nn++) \
        acc[q][(NB)+nn] = __builtin_amdgcn_mfma_f32_16x16x32_bf16( \
            AF[q], BF[nn], acc[q][(NB)+nn], 0, 0, 0); \
    __builtin_amdgcn_s_setprio(0); }while(0)

#define LGKM(n) asm volatile("s_waitcnt lgkmcnt(" #n ")" ::: "memory")
#define SB0  __builtin_amdgcn_sched_barrier(0)
#define BAR  __builtin_amdgcn_s_barrier()
#define VM6  asm volatile("s_waitcnt vmcnt(6)" ::: "memory")
#define VM0  asm volatile("s_waitcnt vmcnt(0)" ::: "memory")
#define VNOP do{}while(0)

  // One K-tile = 4 phases; reads feed the NEXT phase's MFMA.
#define TILE(S, OB0, OT2, SP1, SP4, V4) do{ \
    /* ph1: MFMA(a0,B0k0); in-phase reads a0,bP; ahead-read bQ<=B1k0 */ \
    if (SP1){ STG(pB0, BBASE((S)^1) + 0,    OB0); \
              STG(pB2, BBASE((S)^1) + 8192, OB0); } \
    RD_A(a0, S, 0); RD_B(bP, S, 0, 0); RD_B(bQ, S, 1, 0); \
    LGKM(4); SB0; \
    MMX(a0, bP, 0); \
    BAR; \
    /* ph2: MFMA(a0,B1k0); reads a1<=A k1, bP<=B1k1 */ \
    RD_A(a1, S, 1); RD_B(bP, S, 1, 1); \
    LGKM(8); SB0; \
    MMX(a0, bQ, 4); \
    BAR; \
    /* ph3: MFMA(a1,B1k1); reads bQ<=B0k1 */ \
    RD_B(bQ, S, 0, 1); \
    LGKM(4); SB0; \
    MMX(a1, bP, 4); \
    BAR; \
    /* ph4: MFMA(a1,B0k1); stage A,B1 of tile+2; counted vm drain */ \
    if (SP4){ STG(pA0, ABASE(S) + 0,     OT2); \
              STG(pA1, ABASE(S) + 4096,  OT2); \
              STG(pA2, ABASE(S) + 8192,  OT2); \
              STG(pA3, ABASE(S) + 12288, OT2); \
              STG(pB1, BBASE(S) + 4096,  OT2); \
              STG(pB3, BBASE(S) + 12288, OT2); } \
    LGKM(0); SB0; \
    MMX(a1, bQ, 0); \
    V4; BAR; \
  }while(0)

  int nk = K >> 6;                          // 24 K-tiles
  // ---- prologue: slot0 = tile0 (A,B0,B1 = 8), slot1 = tile1 (A,B1 = 6) ----
  STG(pA0, ABASE(0)+0, 0);     STG(pA1, ABASE(0)+4096, 0);
  STG(pA2, ABASE(0)+8192, 0);  STG(pA3, ABASE(0)+12288, 0);
  STG(pB0, BBASE(0)+0, 0);     STG(pB2, BBASE(0)+8192, 0);
  STG(pB1, BBASE(0)+4096, 0);  STG(pB3, BBASE(0)+12288, 0);
  STG(pA0, ABASE(1)+0, 64);    STG(pA1, ABASE(1)+4096, 64);
  STG(pA2, ABASE(1)+8192, 64); STG(pA3, ABASE(1)+12288, 64);
  STG(pB1, BBASE(1)+4096, 64); STG(pB3, BBASE(1)+12288, 64);
  VM6; BAR;                                 // tile0 landed; tile1's 6 in flight

  for (int tt = 0; tt < (nk-2)/2; ++tt){
    TILE(0,  64, 128, 1, 1, VM6);
    TILE(1, 128, 192, 1, 1, VM6);
    pA0 += 128; pA1 += 128; pA2 += 128; pA3 += 128;
    pB0 += 128; pB1 += 128; pB2 += 128; pB3 += 128;
  }
  TILE(0, 64, 0, 1, 0, VM0);                // tile nk-2: stages B0_{nk-1}
  TILE(1, 0, 0, 0, 0, VNOP);                // tile nk-1

#undef TILE
#undef RD_A
#undef RD_B
#undef STG
#undef MMX

  // ---- epilogue: C/D layout col=lane&15, row=(lane>>4)*4+j ----
  int colb = bcol + wc*128 + fr;
  float bv[8];
  #pragma unroll
  for (int n=0;n<8;n++) bv[n] = bias[colb + n*16];
  int r0 = brow + wr*64 + (lane>>4)*4;
  #pragma unroll
  for (int q=0;q<4;q++){
    #pragma unroll
    for (int j=0;j<4;j++){
      int r = r0 + q*16 + j;
      #pragma unroll
      for (int n=0;n<8;n++){
        float x = acc[q][n][j] + bv[n];
        x = x / (1.0f + expf(-x));
        C[(size_t)r*N + colb + n*16] = f2bf(x);
      }
    }
  }
}

// ---------------------------------------------------------------------------
// bf16 MFMA GEMM (m97 structure, 128x128): used for GEMM2.
template<bool SILU, bool OUT_BF16>
__global__ __launch_bounds__(256) void gemm_mfma_kernel(
  const unsigned short* __restrict__ A, const unsigned short* __restrict__ Bt,
  const float* __restrict__ bias, void* __restrict__ C,
  int M, int N, int K)
{
  __shared__ unsigned short As[128*32];
  __shared__ unsigned short Bs[128*32];
  int nbx = N >> 7;
  int bx = blockIdx.x % nbx;
  int by = blockIdx.x / nbx;
  int tid  = threadIdx.x;
  int lane = tid & 63;
  int wid  = tid >> 6;
  int wr = wid >> 1, wc = wid & 1;
  const int brow = by*128, bcol = bx*128;

  int g_r = lane >> 2;
  int g_k = (lane & 3) * 8;
  const unsigned short* Ag0 = A  + (size_t)(brow + wid*32 + g_r)*K + g_k;
  const unsigned short* Ag1 = Ag0 + (size_t)16*K;
  const unsigned short* Bg0 = Bt + (size_t)(bcol + wid*32 + g_r)*K + g_k;
  const unsigned short* Bg1 = Bg0 + (size_t)16*K;
  unsigned short* lA0 = &As[(wid*32 +  0)*32];
  unsigned short* lA1 = &As[(wid*32 + 16)*32];
  unsigned short* lB0 = &Bs[(wid*32 +  0)*32];
  unsigned short* lB1 = &Bs[(wid*32 + 16)*32];

  f32x4 acc[4][4];
  #pragma unroll
  for (int i=0;i<4;i++)
    #pragma unroll
    for (int j=0;j<4;j++) acc[i][j] = (f32x4){0.f,0.f,0.f,0.f};

  int fr = lane & 15;
  int fk = (lane >> 4) * 8;

  for (int kt = 0; kt < K; kt += 32){
    GL16(Ag0 + kt, lA0);
    GL16(Ag1 + kt, lA1);
    GL16(Bg0 + kt, lB0);
    GL16(Bg1 + kt, lB1);
    __syncthreads();
    bf16x8 af[4], bfr[4];
    #pragma unroll
    for (int i=0;i<4;i++){
      af[i]  = *(const bf16x8*)&As[(wr*64 + i*16 + fr)*32 + fk];
      bfr[i] = *(const bf16x8*)&Bs[(wc*64 + i*16 + fr)*32 + fk];
    }
    #pragma unroll
    for (int mi=0;mi<4;mi++)
      #pragma unroll
      for (int ni=0;ni<4;ni++)
        acc[mi][ni] = __builtin_amdgcn_mfma_f32_16x16x32_bf16(af[mi], bfr[ni], acc[mi][ni], 0, 0, 0);
    __syncthreads();
  }

  int col0 = bcol + wc*64 + (lane & 15);
  int row0 = brow + wr*64 + (lane >> 4)*4;
  #pragma unroll
  for (int mi=0;mi<4;mi++){
    #pragma unroll
    for (int j=0;j<4;j++){
      int r = row0 + mi*16 + j;
      #pragma unroll
      for (int ni=0;ni<4;ni++){
        int c = col0 + ni*16;
        float x = acc[mi][ni][j] + bias[c];
        if (SILU) x = x / (1.0f + expf(-x));
        if (OUT_BF16) ((unsigned short*)C)[(size_t)r*N + c] = f2bf(x);
        else          ((float*)C)[(size_t)r*N + c] = x;
      }
    }
  }
}

// ---------------------------------------------------------------------------
// Parallel merge metadata: one block of 512 threads per batch (thread = position).
__global__ __launch_bounds__(512) void merge_meta_kernel(
  const void* __restrict__ maskp, const int* __restrict__ gid,
  const int* __restrict__ flag,
  int* __restrict__ src, int* __restrict__ count)
{
  int b = blockIdx.x;
  int i = threadIdx.x;
  int lane = i & 63, w = i >> 6;
  __shared__ int sg[Ll_];
  __shared__ int fv[8];
  __shared__ int wt[8];
  int f = *flag;
  int mv;
  if (f==0)      mv = ((const int*)maskp)[b*Ll_+i];
  else if (f==1) mv = ((const unsigned char*)maskp)[b*Ll_+i];
  else           mv = (((const float*)maskp)[b*Ll_+i] != 0.0f);
  bool m = (mv != 0);
  int g = gid[b*Ll_+i];
  sg[i] = g;
  unsigned long long W = __ballot(m);
  if (lane==0) fv[w] = W ? (w*64 + __builtin_ctzll(W)) : -1;
  __syncthreads();
  unsigned long long rem = (lane==63) ? 0ull : (W >> (lane+1));
  int nxtpos = -1;
  if (rem) nxtpos = w*64 + lane + 1 + __builtin_ctzll(rem);
  else {
    #pragma unroll
    for (int k=0;k<8;k++)
      if (nxtpos < 0 && k > w && fv[k] >= 0) nxtpos = fv[k];
  }
  int nxt = (nxtpos >= 0) ? sg[nxtpos] : -1;
  bool sep = m && (nxt >= 0) && (nxt != g);
  int ci = (m?1:0) + (sep?1:0);
  int v = ci;
  #pragma unroll
  for (int off=1; off<64; off<<=1){
    int u = __shfl_up(v, off);
    if (lane >= off) v += u;
  }
  if (lane==63) wt[w] = v;
  __syncthreads();
  int woff = 0;
  #pragma unroll
  for (int k=0;k<8;k++) if (k < w) woff += wt[k];
  int e = woff + v - ci;
  int* sb = src + b*Mm_;
  if (m){
    sb[e] = 2*i;
    if (sep) sb[e+1] = 2*i+1;
  }
  if (i==0){
    int tot=0;
    #pragma unroll
    for (int k=0;k<8;k++) tot += wt[k];
    count[b] = tot;
  }
}

// ---------------------------------------------------------------------------
// Final output: right-aligned pieces + pos_emb, zeros elsewhere, plus mask plane.
__global__ __launch_bounds__(256) void output_kernel(
  const float* __restrict__ ev, const float* __restrict__ pos_emb,
  const float* __restrict__ sep_token,
  const int* __restrict__ src, const int* __restrict__ count,
  float* __restrict__ out)
{
  int tid  = threadIdx.x;
  int tpos = blockIdx.x*4 + (tid>>6);
  int lane = tid & 63;
  int b = tpos >> 10;
  int t = tpos & 1023;
  int cnt = count[b];
  int start = Mm_ - cnt;
  float4 val = make_float4(0.f,0.f,0.f,0.f);
  float maskv = 0.f;
  if (t >= start){
    maskv = 1.f;
    int slot = src[b*Mm_ + (t - start)];
    const float* sv = (slot & 1) ? sep_token
                                 : ev + (size_t)(b*Ll_ + (slot>>1))*Hh;
    float4 x = *(const float4*)(sv + lane*4);
    float4 p = *(const float4*)(pos_emb + (size_t)t*Hh + lane*4);
    val = make_float4(x.x+p.x, x.y+p.y, x.z+p.z, x.w+p.w);
  }
  *(float4*)(out + (size_t)tpos*Hh + lane*4) = val;
  if (lane==0) out[(size_t)Bb_*Mm_*Hh + tpos] = maskv;
}

// ---------------------------------------------------------------------------
extern "C" void kernel_launch(void* const* d_in, const int* in_sizes, int n_in,
                              void* d_out, int out_size, void* d_ws, size_t ws_size,
                              hipStream_t stream) {
  const int* tok    = (const int*)d_in[0];
  const int* post   = (const int*)d_in[1];
  const int* auth   = (const int*)d_in[2];
  const int* act    = (const int*)d_in[3];
  const int* tg     = (const int*)d_in[4];
  const int* gid    = (const int*)d_in[5];
  const void* maskp =             d_in[6];
  const float* token_emb = (const float*)d_in[7];
  const float* time_emb  = (const float*)d_in[8];
  const float* group_emb = (const float*)d_in[9];
  const float* pos_emb   = (const float*)d_in[10];
  const float* sep_token = (const float*)d_in[11];
  const float* ln_g = (const float*)d_in[12];
  const float* ln_b = (const float*)d_in[13];
  const float* W1   = (const float*)d_in[14];
  const float* b1   = (const float*)d_in[15];
  const float* W2   = (const float*)d_in[16];
  const float* b2   = (const float*)d_in[17];

  char* ws = (char*)d_ws;
  size_t off = 0;
  int* flag = (int*)ws;                                  off += 256;
  unsigned short* xn  = (unsigned short*)(ws + off);     off += (size_t)BL_*SIXH*2;
  unsigned short* h1  = (unsigned short*)(ws + off);     off += (size_t)BL_*N1_*2;
  float*          ev  = (float*)(ws + off);              off += (size_t)BL_*N2_*4;
  unsigned short* w1t = (unsigned short*)(ws + off);     off += (size_t)K1_*N1_*2;
  unsigned short* w2t = (unsigned short*)(ws + off);     off += (size_t)K2_*N2_*2;
  int*            src = (int*)(ws + off);                off += (size_t)Bb_*Mm_*4;
  int*            cnt = (int*)(ws + off);                off += 256;

  detect_mask_kernel<<<1,256,0,stream>>>((const unsigned int*)maskp, flag);
  transpose_conv_kernel<<<(K1_/32)*(N1_/32),256,0,stream>>>(W1, w1t, K1_, N1_);
  transpose_conv_kernel<<<(K2_/32)*(N2_/32),256,0,stream>>>(W2, w2t, K2_, N2_);
  gather_ln_kernel<<<BL_,256,0,stream>>>(tok,post,auth,act,tg,gid,
                                         token_emb,time_emb,group_emb,
                                         ln_g,ln_b,xn);
  gemm1_ov_kernel<<<(BL_/256)*(N1_/256),512,0,stream>>>(
      xn, w1t, b1, h1, BL_, N1_, K1_);
  gemm_mfma_kernel<false,false><<<(BL_/128)*(N2_/128),256,0,stream>>>(
      h1, w2t, b2, (void*)ev, BL_, N2_, K2_);
  merge_meta_kernel<<<Bb_,512,0,stream>>>(maskp, gid, flag, src, cnt);
  output_kernel<<<(Bb_*Mm_)/4,256,0,stream>>>(ev, pos_emb, sep_token, src, cnt, (float*)d_out);
}

// Round 6
// 137.217 us; speedup vs baseline: 1.0056x; 1.0056x over previous
//
#include <hip/hip_runtime.h>
#include <string.h>

// Problem constants (from reference setup_inputs)
#define Hh   256
#define SIXH 1536
#define Bb_  32
#define Ll_  512
#define BL_  16384   // B*L
#define Mm_  1024
#define N1_  1024    // 4H
#define K1_  1536    // 6H
#define K2_  1024
#define N2_  256

typedef __attribute__((ext_vector_type(8))) short bf16x8;
typedef __attribute__((ext_vector_type(4))) float f32x4;

__device__ inline float bf2f(unsigned short u){ unsigned x=(unsigned)u<<16; float f; memcpy(&f,&x,4); return f; }
__device__ inline unsigned short f2bf(float f){ unsigned x; memcpy(&x,&f,4); x = x + 0x7FFFu + ((x>>16)&1u); return (unsigned short)(x>>16); }

#define GL16(gp, lp) __builtin_amdgcn_global_load_lds( \
    (const __attribute__((address_space(1))) void*)(gp), \
    (__attribute__((address_space(3))) void*)(lp), 16, 0, 0)

// ---------------------------------------------------------------------------
// Mask dtype detection: flag 0 = int32, 1 = byte(bool), 2 = float32.
__global__ void detect_mask_kernel(const unsigned int* __restrict__ m, int* __restrict__ flag){
  int t = threadIdx.x;
  bool gt1=false, isf=false;
  for (int i=t;i<4096;i+=256){ unsigned v=m[i]; if(v>1u) gt1=true; if(v==0x3F800000u) isf=true; }
  unsigned long long bg = __ballot(gt1), bf = __ballot(isf);
  __shared__ unsigned long long s1[4], s2[4];
  int w = t>>6;
  if ((t&63)==0){ s1[w]=bg; s2[w]=bf; }
  __syncthreads();
  if (t==0){
    bool g = (s1[0]|s1[1]|s1[2]|s1[3])!=0ull;
    bool f = (s2[0]|s2[1]|s2[2]|s2[3])!=0ull;
    *flag = g ? (f?2:1) : 0;
  }
}

// ---------------------------------------------------------------------------
// Tiled transpose + fp32->bf16 convert: W [K][N] f32  ->  Wt [N][K] bf16.
__global__ __launch_bounds__(256) void transpose_conv_kernel(
  const float* __restrict__ W, unsigned short* __restrict__ Wt, int K, int N)
{
  __shared__ float t[32][33];
  int ntx = N >> 5;
  int bx = blockIdx.x % ntx;
  int by = blockIdx.x / ntx;
  int tx = threadIdx.x & 31, ty = threadIdx.x >> 5;
  #pragma unroll
  for (int i=0;i<32;i+=8)
    t[ty+i][tx] = W[(size_t)(by*32+ty+i)*N + bx*32+tx];
  __syncthreads();
  #pragma unroll
  for (int i=0;i<32;i+=8)
    Wt[(size_t)(bx*32+ty+i)*K + by*32+tx] = f2bf(t[tx][ty+i]);
}

// ---------------------------------------------------------------------------
// Gather 6 embedding segments + LayerNorm(1536) -> xn bf16 [16384][1536]
__global__ __launch_bounds__(256) void gather_ln_kernel(
  const int* __restrict__ tok, const int* __restrict__ post,
  const int* __restrict__ auth, const int* __restrict__ act,
  const int* __restrict__ tg,  const int* __restrict__ gidp,
  const float* __restrict__ token_emb, const float* __restrict__ time_emb,
  const float* __restrict__ group_emb,
  const float* __restrict__ ln_g, const float* __restrict__ ln_b,
  unsigned short* __restrict__ xn)
{
  int row = blockIdx.x;
  int t   = threadIdx.x;
  int i0 = tok[row], i1 = post[row], i2 = auth[row], i3 = act[row];
  int i4 = tg[row]; i4 = (i4 < 0) ? 0 : (i4 > 64 ? 64 : i4);
  int i5 = gidp[row];
  float v[6];
  v[0] = token_emb[(size_t)i0*Hh + t];
  v[1] = token_emb[(size_t)i1*Hh + t];
  v[2] = token_emb[(size_t)i2*Hh + t];
  v[3] = token_emb[(size_t)i3*Hh + t];
  v[4] = time_emb[i4*Hh + t];
  v[5] = group_emb[i5*Hh + t];
  float s=0.f, s2=0.f;
  #pragma unroll
  for (int i=0;i<6;i++){ s+=v[i]; s2+=v[i]*v[i]; }
  #pragma unroll
  for (int off=32; off; off>>=1){ s += __shfl_xor(s,off); s2 += __shfl_xor(s2,off); }
  __shared__ float rs[4], rs2[4];
  int w=t>>6;
  if ((t&63)==0){ rs[w]=s; rs2[w]=s2; }
  __syncthreads();
  s  = rs[0]+rs[1]+rs[2]+rs[3];
  s2 = rs2[0]+rs2[1]+rs2[2]+rs2[3];
  float mu   = s * (1.0f/1536.0f);
  float var  = s2 * (1.0f/1536.0f) - mu*mu;
  float rstd = rsqrtf(var + 1e-5f);
  unsigned short* xr = xn + (size_t)row*SIXH;
  #pragma unroll
  for (int i=0;i<6;i++){
    int j = i*Hh + t;
    float y = (v[i]-mu)*rstd*ln_g[j] + ln_b[j];
    xr[j] = f2bf(y);
  }
}

// ---------------------------------------------------------------------------
// GEMM1: 256x256 tile, 8 waves (4x2 grid, wave = 64 rows x 128 cols), BK=64.
// ONE BARRIER PER K-TILE: waves drift freely across the 4 intra-tile phases
// (sealed only by per-wave counted lgkmcnt), so one wave's MFMA overlaps
// another wave's LDS-port drain (the stagger lockstep barriers destroyed —
// R1..R5 all pinned at ~33% MfmaUtil with 4-8 barriers/K-tile).
// Per K-tile T (reads slot S=T&1): {stage tile T+1 -> slot S^1 (8x GL16,
// issued right after the prior barrier, ~full-tile flight); 4 read-ahead
// phases; vmcnt(0) (nearly free); s_barrier}. Safety: the end-of-T barrier
// orders [all waves' reads of S^1 done (own ph4 lgkmcnt(0) precedes it)] and
// [all waves' stages drained (own vmcnt(0) precedes it)] -> no read/write
// races, tile T+1 fully published.
// LDS: A slot s at s*16384 elems; B at 32768 + s*16384. 128 KiB.
// Swizzle: 16B granule g of row r stored at g ^ (r&7) (involution both sides;
// measured 0 bank conflicts). Addressing identical to R5 (correctness-proven).
// A [M][K] bf16, Bt [N][K] bf16, C = silu(A@Bt^T + bias) as bf16 [M][N].
__global__ __launch_bounds__(512, 2) void gemm1_nb_kernel(
  const unsigned short* __restrict__ A, const unsigned short* __restrict__ Bt,
  const float* __restrict__ bias, unsigned short* __restrict__ C,
  int M, int N, int K)
{
  __shared__ unsigned short lds[65536];

  int nbx = N >> 8;
  int bid = blockIdx.x;
  if ((gridDim.x & 7) == 0){                // XCD swizzle (bijective, nwg%8==0)
    int chunk = gridDim.x >> 3;
    bid = (bid & 7)*chunk + (bid >> 3);
  }
  int bx = bid % nbx, by = bid / nbx;
  int brow = by*256, bcol = bx*256;

  int tid = threadIdx.x, lane = tid & 63, wid = tid >> 6;
  int wr = wid >> 1, wc = wid & 1;          // 4 x 2 wave grid

  // ---- staging lane geometry: 64-row GL16 rounds (pre-swizzled global) ----
  int sRow = tid >> 3;                      // 0..63
  int sSw  = ((tid & 7) ^ (sRow & 7)) << 3; // swizzled granule (elements)
  const unsigned short* pA0 = A  + (size_t)(brow +   0 + sRow)*K + sSw;
  const unsigned short* pA1 = A  + (size_t)(brow +  64 + sRow)*K + sSw;
  const unsigned short* pA2 = A  + (size_t)(brow + 128 + sRow)*K + sSw;
  const unsigned short* pA3 = A  + (size_t)(brow + 192 + sRow)*K + sSw;
  const unsigned short* pB0 = Bt + (size_t)(bcol +   0 + sRow)*K + sSw;
  const unsigned short* pB1 = Bt + (size_t)(bcol +  64 + sRow)*K + sSw;
  const unsigned short* pB2 = Bt + (size_t)(bcol + 128 + sRow)*K + sSw;
  const unsigned short* pB3 = Bt + (size_t)(bcol + 192 + sRow)*K + sSw;

  // ---- per-lane fragment read bases (swizzled), in elements ----
  int fr = lane & 15, kb = lane >> 4;
  int g0 = (kb ^ (fr & 3)) | (fr & 4);      // = kb ^ (fr&7); kc=1 -> addr ^32
  int aB = (wr*64  + fr)*64 + g0*8;
  int bB = (wc*128 + fr)*64 + g0*8;

  f32x4 acc[4][8];
  #pragma unroll
  for (int q=0;q<4;q++)
    #pragma unroll
    for (int n=0;n<8;n++) acc[q][n] = (f32x4){0.f,0.f,0.f,0.f};

  bf16x8 a0[4], a1[4], bP[4], bQ[4];        // 16 frags = 64 VGPR

#define ABASE(S) ((S)*16384)
#define BBASE(S) (32768 + (S)*16384)

#define RD_A(buf, S, kc) do{ \
    const unsigned short* L_ = lds + ABASE(S) + (aB ^ ((kc)?32:0)); \
    buf[0] = *(const bf16x8*)(L_); \
    buf[1] = *(const bf16x8*)(L_ + 1024); \
    buf[2] = *(const bf16x8*)(L_ + 2048); \
    buf[3] = *(const bf16x8*)(L_ + 3072); }while(0)

#define RD_B(buf, S, h, kc) do{ \
    const unsigned short* L_ = lds + BBASE(S) + (h)*4096 + (bB ^ ((kc)?32:0)); \
    buf[0] = *(const bf16x8*)(L_); \
    buf[1] = *(const bf16x8*)(L_ + 1024); \
    buf[2] = *(const bf16x8*)(L_ + 2048); \
    buf[3] = *(const bf16x8*)(L_ + 3072); }while(0)

  // one GL16 round = 512 threads x 16B = 64 rows; linear LDS dest.
#define STG(p, DB, OFF) GL16((p) + (OFF), lds + (DB) + wid*512)

#define MMX(AF, BF, NB) do{ \
    __builtin_amdgcn_s_setprio(1); \
    _Pragma("unroll") for (int q=0;q<4;q++) \
      _Pragma("unroll") for (int nn=0;nn<4;nn++) \
        acc[q][(NB)+nn] = __builtin_amdgcn_mfma_f32_16x16x32_bf16( \
            AF[q], BF[nn], acc[q][(NB)+nn], 0, 0, 0); \
    __builtin_amdgcn_s_setprio(0); }while(0)

#define LGKM(n) asm volatile("s_waitcnt lgkmcnt(" #n ")" ::: "memory")
#define SB0  __builtin_amdgcn_sched_barrier(0)
#define BAR  __builtin_amdgcn_s_barrier()
#define VM0  asm volatile("s_waitcnt vmcnt(0)" ::: "memory")
#define VNOP do{}while(0)

  // One K-tile: no intra-tile barriers; one vmcnt(0)+barrier at the end.
  // SP: stage tile T+1 -> slot S^1 at relative k-offset OB1.
#define TILE(S, OB1, SP, V4) do{ \
    /* ph1: reads a0,bP (this phase) + bQ (ahead) */ \
    RD_A(a0, S, 0); RD_B(bP, S, 0, 0); RD_B(bQ, S, 1, 0); \
    if (SP){ \
      STG(pA0, ABASE((S)^1) + 0,     OB1); \
      STG(pA1, ABASE((S)^1) + 4096,  OB1); \
      STG(pA2, ABASE((S)^1) + 8192,  OB1); \
      STG(pA3, ABASE((S)^1) + 12288, OB1); \
      STG(pB0, BBASE((S)^1) + 0,     OB1); \
      STG(pB1, BBASE((S)^1) + 4096,  OB1); \
      STG(pB2, BBASE((S)^1) + 8192,  OB1); \
      STG(pB3, BBASE((S)^1) + 12288, OB1); } \
    LGKM(4); SB0; \
    MMX(a0, bP, 0); \
    /* ph2 */ \
    RD_A(a1, S, 1); RD_B(bP, S, 1, 1); \
    LGKM(8); SB0; \
    MMX(a0, bQ, 4); \
    /* ph3 */ \
    RD_B(bQ, S, 0, 1); \
    LGKM(4); SB0; \
    MMX(a1, bP, 4); \
    /* ph4 */ \
    LGKM(0); SB0; \
    MMX(a1, bQ, 0); \
    V4; BAR; \
  }while(0)

  int nk = K >> 6;                          // 24 K-tiles
  // ---- prologue: stage tile 0 -> slot 0; publish ----
  STG(pA0, ABASE(0)+0, 0);     STG(pA1, ABASE(0)+4096, 0);
  STG(pA2, ABASE(0)+8192, 0);  STG(pA3, ABASE(0)+12288, 0);
  STG(pB0, BBASE(0)+0, 0);     STG(pB1, BBASE(0)+4096, 0);
  STG(pB2, BBASE(0)+8192, 0);  STG(pB3, BBASE(0)+12288, 0);
  VM0; BAR;

  for (int tt = 0; tt < (nk-2)/2; ++tt){
    TILE(0,  64, 1, VM0);                   // T even: stages T+1 -> slot 1
    TILE(1, 128, 1, VM0);                   // T odd : stages T+2 -> slot 0
    pA0 += 128; pA1 += 128; pA2 += 128; pA3 += 128;
    pB0 += 128; pB1 += 128; pB2 += 128; pB3 += 128;
  }
  TILE(0, 64, 1, VM0);                      // T=nk-2: stages nk-1 -> slot 1
  TILE(1, 0, 0, VNOP);                      // T=nk-1: no staging

#undef TILE
#undef RD_A
#undef RD_B
#undef STG
#undef MMX

  // ---- epilogue: C/D layout col=lane&15, row=(lane>>4)*4+j ----
  int colb = bcol + wc*128 + fr;
  float bv[8];
  #pragma unroll
  for (int n=0;n<8;n++) bv[n] = bias[colb + n*16];
  int r0 = brow + wr*64 + (lane>>4)*4;
  #pragma unroll
  for (int q=0;q<4;q++){
    #pragma unroll
    for (int j=0;j<4;j++){
      int r = r0 + q*16 + j;
      #pragma unroll
      for (int n=0;n<8;n++){
        float x = acc[q][n][j] + bv[n];
        x = x / (1.0f + expf(-x));
        C[(size_t)r*N + colb + n*16] = f2bf(x);
      }
    }
  }
}

// ---------------------------------------------------------------------------
// bf16 MFMA GEMM (m97 structure, 128x128): used for GEMM2.
template<bool SILU, bool OUT_BF16>
__global__ __launch_bounds__(256) void gemm_mfma_kernel(
  const unsigned short* __restrict__ A, const unsigned short* __restrict__ Bt,
  const float* __restrict__ bias, void* __restrict__ C,
  int M, int N, int K)
{
  __shared__ unsigned short As[128*32];
  __shared__ unsigned short Bs[128*32];
  int nbx = N >> 7;
  int bx = blockIdx.x % nbx;
  int by = blockIdx.x / nbx;
  int tid  = threadIdx.x;
  int lane = tid & 63;
  int wid  = tid >> 6;
  int wr = wid >> 1, wc = wid & 1;
  const int brow = by*128, bcol = bx*128;

  int g_r = lane >> 2;
  int g_k = (lane & 3) * 8;
  const unsigned short* Ag0 = A  + (size_t)(brow + wid*32 + g_r)*K + g_k;
  const unsigned short* Ag1 = Ag0 + (size_t)16*K;
  const unsigned short* Bg0 = Bt + (size_t)(bcol + wid*32 + g_r)*K + g_k;
  const unsigned short* Bg1 = Bg0 + (size_t)16*K;
  unsigned short* lA0 = &As[(wid*32 +  0)*32];
  unsigned short* lA1 = &As[(wid*32 + 16)*32];
  unsigned short* lB0 = &Bs[(wid*32 +  0)*32];
  unsigned short* lB1 = &Bs[(wid*32 + 16)*32];

  f32x4 acc[4][4];
  #pragma unroll
  for (int i=0;i<4;i++)
    #pragma unroll
    for (int j=0;j<4;j++) acc[i][j] = (f32x4){0.f,0.f,0.f,0.f};

  int fr = lane & 15;
  int fk = (lane >> 4) * 8;

  for (int kt = 0; kt < K; kt += 32){
    GL16(Ag0 + kt, lA0);
    GL16(Ag1 + kt, lA1);
    GL16(Bg0 + kt, lB0);
    GL16(Bg1 + kt, lB1);
    __syncthreads();
    bf16x8 af[4], bfr[4];
    #pragma unroll
    for (int i=0;i<4;i++){
      af[i]  = *(const bf16x8*)&As[(wr*64 + i*16 + fr)*32 + fk];
      bfr[i] = *(const bf16x8*)&Bs[(wc*64 + i*16 + fr)*32 + fk];
    }
    #pragma unroll
    for (int mi=0;mi<4;mi++)
      #pragma unroll
      for (int ni=0;ni<4;ni++)
        acc[mi][ni] = __builtin_amdgcn_mfma_f32_16x16x32_bf16(af[mi], bfr[ni], acc[mi][ni], 0, 0, 0);
    __syncthreads();
  }

  int col0 = bcol + wc*64 + (lane & 15);
  int row0 = brow + wr*64 + (lane >> 4)*4;
  #pragma unroll
  for (int mi=0;mi<4;mi++){
    #pragma unroll
    for (int j=0;j<4;j++){
      int r = row0 + mi*16 + j;
      #pragma unroll
      for (int ni=0;ni<4;ni++){
        int c = col0 + ni*16;
        float x = acc[mi][ni][j] + bias[c];
        if (SILU) x = x / (1.0f + expf(-x));
        if (OUT_BF16) ((unsigned short*)C)[(size_t)r*N + c] = f2bf(x);
        else          ((float*)C)[(size_t)r*N + c] = x;
      }
    }
  }
}

// ---------------------------------------------------------------------------
// Parallel merge metadata: one block of 512 threads per batch (thread = position).
__global__ __launch_bounds__(512) void merge_meta_kernel(
  const void* __restrict__ maskp, const int* __restrict__ gid,
  const int* __restrict__ flag,
  int* __restrict__ src, int* __restrict__ count)
{
  int b = blockIdx.x;
  int i = threadIdx.x;
  int lane = i & 63, w = i >> 6;
  __shared__ int sg[Ll_];
  __shared__ int fv[8];
  __shared__ int wt[8];
  int f = *flag;
  int mv;
  if (f==0)      mv = ((const int*)maskp)[b*Ll_+i];
  else if (f==1) mv = ((const unsigned char*)maskp)[b*Ll_+i];
  else           mv = (((const float*)maskp)[b*Ll_+i] != 0.0f);
  bool m = (mv != 0);
  int g = gid[b*Ll_+i];
  sg[i] = g;
  unsigned long long W = __ballot(m);
  if (lane==0) fv[w] = W ? (w*64 + __builtin_ctzll(W)) : -1;
  __syncthreads();
  unsigned long long rem = (lane==63) ? 0ull : (W >> (lane+1));
  int nxtpos = -1;
  if (rem) nxtpos = w*64 + lane + 1 + __builtin_ctzll(rem);
  else {
    #pragma unroll
    for (int k=0;k<8;k++)
      if (nxtpos < 0 && k > w && fv[k] >= 0) nxtpos = fv[k];
  }
  int nxt = (nxtpos >= 0) ? sg[nxtpos] : -1;
  bool sep = m && (nxt >= 0) && (nxt != g);
  int ci = (m?1:0) + (sep?1:0);
  int v = ci;
  #pragma unroll
  for (int off=1; off<64; off<<=1){
    int u = __shfl_up(v, off);
    if (lane >= off) v += u;
  }
  if (lane==63) wt[w] = v;
  __syncthreads();
  int woff = 0;
  #pragma unroll
  for (int k=0;k<8;k++) if (k < w) woff += wt[k];
  int e = woff + v - ci;
  int* sb = src + b*Mm_;
  if (m){
    sb[e] = 2*i;
    if (sep) sb[e+1] = 2*i+1;
  }
  if (i==0){
    int tot=0;
    #pragma unroll
    for (int k=0;k<8;k++) tot += wt[k];
    count[b] = tot;
  }
}

// ---------------------------------------------------------------------------
// Final output: right-aligned pieces + pos_emb, zeros elsewhere, plus mask plane.
__global__ __launch_bounds__(256) void output_kernel(
  const float* __restrict__ ev, const float* __restrict__ pos_emb,
  const float* __restrict__ sep_token,
  const int* __restrict__ src, const int* __restrict__ count,
  float* __restrict__ out)
{
  int tid  = threadIdx.x;
  int tpos = blockIdx.x*4 + (tid>>6);
  int lane = tid & 63;
  int b = tpos >> 10;
  int t = tpos & 1023;
  int cnt = count[b];
  int start = Mm_ - cnt;
  float4 val = make_float4(0.f,0.f,0.f,0.f);
  float maskv = 0.f;
  if (t >= start){
    maskv = 1.f;
    int slot = src[b*Mm_ + (t - start)];
    const float* sv = (slot & 1) ? sep_token
                                 : ev + (size_t)(b*Ll_ + (slot>>1))*Hh;
    float4 x = *(const float4*)(sv + lane*4);
    float4 p = *(const float4*)(pos_emb + (size_t)t*Hh + lane*4);
    val = make_float4(x.x+p.x, x.y+p.y, x.z+p.z, x.w+p.w);
  }
  *(float4*)(out + (size_t)tpos*Hh + lane*4) = val;
  if (lane==0) out[(size_t)Bb_*Mm_*Hh + tpos] = maskv;
}

// ---------------------------------------------------------------------------
extern "C" void kernel_launch(void* const* d_in, const int* in_sizes, int n_in,
                              void* d_out, int out_size, void* d_ws, size_t ws_size,
                              hipStream_t stream) {
  const int* tok    = (const int*)d_in[0];
  const int* post   = (const int*)d_in[1];
  const int* auth   = (const int*)d_in[2];
  const int* act    = (const int*)d_in[3];
  const int* tg     = (const int*)d_in[4];
  const int* gid    = (const int*)d_in[5];
  const void* maskp =             d_in[6];
  const float* token_emb = (const float*)d_in[7];
  const float* time_emb  = (const float*)d_in[8];
  const float* group_emb = (const float*)d_in[9];
  const float* pos_emb   = (const float*)d_in[10];
  const float* sep_token = (const float*)d_in[11];
  const float* ln_g = (const float*)d_in[12];
  const float* ln_b = (const float*)d_in[13];
  const float* W1   = (const float*)d_in[14];
  const float* b1   = (const float*)d_in[15];
  const float* W2   = (const float*)d_in[16];
  const float* b2   = (const float*)d_in[17];

  char* ws = (char*)d_ws;
  size_t off = 0;
  int* flag = (int*)ws;                                  off += 256;
  unsigned short* xn  = (unsigned short*)(ws + off);     off += (size_t)BL_*SIXH*2;
  unsigned short* h1  = (unsigned short*)(ws + off);     off += (size_t)BL_*N1_*2;
  float*          ev  = (float*)(ws + off);              off += (size_t)BL_*N2_*4;
  unsigned short* w1t = (unsigned short*)(ws + off);     off += (size_t)K1_*N1_*2;
  unsigned short* w2t = (unsigned short*)(ws + off);     off += (size_t)K2_*N2_*2;
  int*            src = (int*)(ws + off);                off += (size_t)Bb_*Mm_*4;
  int*            cnt = (int*)(ws + off);                off += 256;

  detect_mask_kernel<<<1,256,0,stream>>>((const unsigned int*)maskp, flag);
  transpose_conv_kernel<<<(K1_/32)*(N1_/32),256,0,stream>>>(W1, w1t, K1_, N1_);
  transpose_conv_kernel<<<(K2_/32)*(N2_/32),256,0,stream>>>(W2, w2t, K2_, N2_);
  gather_ln_kernel<<<BL_,256,0,stream>>>(tok,post,auth,act,tg,gid,
                                         token_emb,time_emb,group_emb,
                                         ln_g,ln_b,xn);
  gemm1_nb_kernel<<<(BL_/256)*(N1_/256),512,0,stream>>>(
      xn, w1t, b1, h1, BL_, N1_, K1_);
  gemm_mfma_kernel<false,false><<<(BL_/128)*(N2_/128),256,0,stream>>>(
      h1, w2t, b2, (void*)ev, BL_, N2_, K2_);
  merge_meta_kernel<<<Bb_,512,0,stream>>>(maskp, gid, flag, src, cnt);
  output_kernel<<<(Bb_*Mm_)/4,256,0,stream>>>(ev, pos_emb, sep_token, src, cnt, (float*)d_out);
}

// Round 7
// 137.079 us; speedup vs baseline: 1.0066x; 1.0010x over previous
//
#include <hip/hip_runtime.h>
#include <string.h>

// Problem constants (from reference setup_inputs)
#define Hh   256
#define SIXH 1536
#define Bb_  32
#define Ll_  512
#define BL_  16384   // B*L
#define Mm_  1024
#define N1_  1024    // 4H
#define K1_  1536    // 6H
#define K2_  1024
#define N2_  256

typedef __attribute__((ext_vector_type(8))) short bf16x8;
typedef __attribute__((ext_vector_type(4))) float f32x4;

__device__ inline float bf2f(unsigned short u){ unsigned x=(unsigned)u<<16; float f; memcpy(&f,&x,4); return f; }
__device__ inline unsigned short f2bf(float f){ unsigned x; memcpy(&x,&f,4); x = x + 0x7FFFu + ((x>>16)&1u); return (unsigned short)(x>>16); }

#define GL16(gp, lp) __builtin_amdgcn_global_load_lds( \
    (const __attribute__((address_space(1))) void*)(gp), \
    (__attribute__((address_space(3))) void*)(lp), 16, 0, 0)

// ---------------------------------------------------------------------------
// Mask dtype detection: flag 0 = int32, 1 = byte(bool), 2 = float32.
__global__ void detect_mask_kernel(const unsigned int* __restrict__ m, int* __restrict__ flag){
  int t = threadIdx.x;
  bool gt1=false, isf=false;
  for (int i=t;i<4096;i+=256){ unsigned v=m[i]; if(v>1u) gt1=true; if(v==0x3F800000u) isf=true; }
  unsigned long long bg = __ballot(gt1), bf = __ballot(isf);
  __shared__ unsigned long long s1[4], s2[4];
  int w = t>>6;
  if ((t&63)==0){ s1[w]=bg; s2[w]=bf; }
  __syncthreads();
  if (t==0){
    bool g = (s1[0]|s1[1]|s1[2]|s1[3])!=0ull;
    bool f = (s2[0]|s2[1]|s2[2]|s2[3])!=0ull;
    *flag = g ? (f?2:1) : 0;
  }
}

// ---------------------------------------------------------------------------
// Tiled transpose + fp32->bf16 convert: W [K][N] f32  ->  Wt [N][K] bf16.
__global__ __launch_bounds__(256) void transpose_conv_kernel(
  const float* __restrict__ W, unsigned short* __restrict__ Wt, int K, int N)
{
  __shared__ float t[32][33];
  int ntx = N >> 5;
  int bx = blockIdx.x % ntx;
  int by = blockIdx.x / ntx;
  int tx = threadIdx.x & 31, ty = threadIdx.x >> 5;
  #pragma unroll
  for (int i=0;i<32;i+=8)
    t[ty+i][tx] = W[(size_t)(by*32+ty+i)*N + bx*32+tx];
  __syncthreads();
  #pragma unroll
  for (int i=0;i<32;i+=8)
    Wt[(size_t)(bx*32+ty+i)*K + by*32+tx] = f2bf(t[tx][ty+i]);
}

// ---------------------------------------------------------------------------
// Gather 6 embedding segments + LayerNorm(1536) -> xn bf16 [16384][1536]
__global__ __launch_bounds__(256) void gather_ln_kernel(
  const int* __restrict__ tok, const int* __restrict__ post,
  const int* __restrict__ auth, const int* __restrict__ act,
  const int* __restrict__ tg,  const int* __restrict__ gidp,
  const float* __restrict__ token_emb, const float* __restrict__ time_emb,
  const float* __restrict__ group_emb,
  const float* __restrict__ ln_g, const float* __restrict__ ln_b,
  unsigned short* __restrict__ xn)
{
  int row = blockIdx.x;
  int t   = threadIdx.x;
  int i0 = tok[row], i1 = post[row], i2 = auth[row], i3 = act[row];
  int i4 = tg[row]; i4 = (i4 < 0) ? 0 : (i4 > 64 ? 64 : i4);
  int i5 = gidp[row];
  float v[6];
  v[0] = token_emb[(size_t)i0*Hh + t];
  v[1] = token_emb[(size_t)i1*Hh + t];
  v[2] = token_emb[(size_t)i2*Hh + t];
  v[3] = token_emb[(size_t)i3*Hh + t];
  v[4] = time_emb[i4*Hh + t];
  v[5] = group_emb[i5*Hh + t];
  float s=0.f, s2=0.f;
  #pragma unroll
  for (int i=0;i<6;i++){ s+=v[i]; s2+=v[i]*v[i]; }
  #pragma unroll
  for (int off=32; off; off>>=1){ s += __shfl_xor(s,off); s2 += __shfl_xor(s2,off); }
  __shared__ float rs[4], rs2[4];
  int w=t>>6;
  if ((t&63)==0){ rs[w]=s; rs2[w]=s2; }
  __syncthreads();
  s  = rs[0]+rs[1]+rs[2]+rs[3];
  s2 = rs2[0]+rs2[1]+rs2[2]+rs2[3];
  float mu   = s * (1.0f/1536.0f);
  float var  = s2 * (1.0f/1536.0f) - mu*mu;
  float rstd = rsqrtf(var + 1e-5f);
  unsigned short* xr = xn + (size_t)row*SIXH;
  #pragma unroll
  for (int i=0;i<6;i++){
    int j = i*Hh + t;
    float y = (v[i]-mu)*rstd*ln_g[j] + ln_b[j];
    xr[j] = f2bf(y);
  }
}

// ---------------------------------------------------------------------------
// GEMM1: 256x256 tile, 8 waves (4x2 grid, wave = 64 rows x 128 cols), BK=64.
// COMPILER-SCHEDULED TILE BODY: no intra-tile lgkmcnt/sched_barrier/setprio
// walls (R1-R6 all pinned at 30-35% MfmaUtil with per-phase fences — m141's
// "sched_barrier pinning defeats compiler scheduling" pathology). Plain C++
// ds-reads + MFMAs let the compiler emit fine-grained interleaved lgkmcnt
// (m97-proven near-optimal) so the LDS port drains UNDER the MFMA stream.
// Walls only at tile boundary where the compiler is blind (global_load_lds):
//   lgkmcnt(0)  — seal all slot-S reads before the barrier (WAR vs next stages)
//   vmcnt(0)    — publish tile T+1's stages to LDS
//   s_barrier   — one per K-tile.
// LDS: A slot s at s*16384 elems; B at 32768 + s*16384. 128 KiB.
// Swizzle: 16B granule g of row r stored at g ^ (r&7) (involution both sides;
// measured 0 bank conflicts). Addressing identical to R5/R6 (correctness-proven).
// A [M][K] bf16, Bt [N][K] bf16, C = silu(A@Bt^T + bias) as bf16 [M][N].
__global__ __launch_bounds__(512, 2) void gemm1_cs_kernel(
  const unsigned short* __restrict__ A, const unsigned short* __restrict__ Bt,
  const float* __restrict__ bias, unsigned short* __restrict__ C,
  int M, int N, int K)
{
  __shared__ unsigned short lds[65536];

  int nbx = N >> 8;
  int bid = blockIdx.x;
  if ((gridDim.x & 7) == 0){                // XCD swizzle (bijective, nwg%8==0)
    int chunk = gridDim.x >> 3;
    bid = (bid & 7)*chunk + (bid >> 3);
  }
  int bx = bid % nbx, by = bid / nbx;
  int brow = by*256, bcol = bx*256;

  int tid = threadIdx.x, lane = tid & 63, wid = tid >> 6;
  int wr = wid >> 1, wc = wid & 1;          // 4 x 2 wave grid

  // ---- staging lane geometry: 64-row GL16 rounds (pre-swizzled global) ----
  int sRow = tid >> 3;                      // 0..63
  int sSw  = ((tid & 7) ^ (sRow & 7)) << 3; // swizzled granule (elements)
  const unsigned short* pA0 = A  + (size_t)(brow +   0 + sRow)*K + sSw;
  const unsigned short* pA1 = A  + (size_t)(brow +  64 + sRow)*K + sSw;
  const unsigned short* pA2 = A  + (size_t)(brow + 128 + sRow)*K + sSw;
  const unsigned short* pA3 = A  + (size_t)(brow + 192 + sRow)*K + sSw;
  const unsigned short* pB0 = Bt + (size_t)(bcol +   0 + sRow)*K + sSw;
  const unsigned short* pB1 = Bt + (size_t)(bcol +  64 + sRow)*K + sSw;
  const unsigned short* pB2 = Bt + (size_t)(bcol + 128 + sRow)*K + sSw;
  const unsigned short* pB3 = Bt + (size_t)(bcol + 192 + sRow)*K + sSw;

  // ---- per-lane fragment read bases (swizzled), in elements ----
  int fr = lane & 15, kb = lane >> 4;
  int g0 = (kb ^ (fr & 3)) | (fr & 4);      // = kb ^ (fr&7); kc=1 -> addr ^32
  int aB = (wr*64  + fr)*64 + g0*8;
  int bB = (wc*128 + fr)*64 + g0*8;

  f32x4 acc[4][8];
  #pragma unroll
  for (int q=0;q<4;q++)
    #pragma unroll
    for (int n=0;n<8;n++) acc[q][n] = (f32x4){0.f,0.f,0.f,0.f};

  bf16x8 a0[4], a1[4], bP[4], bQ[4];        // 16 frags = 64 VGPR

#define ABASE(S) ((S)*16384)
#define BBASE(S) (32768 + (S)*16384)

#define RD_A(buf, S, kc) do{ \
    const unsigned short* L_ = lds + ABASE(S) + (aB ^ ((kc)?32:0)); \
    buf[0] = *(const bf16x8*)(L_); \
    buf[1] = *(const bf16x8*)(L_ + 1024); \
    buf[2] = *(const bf16x8*)(L_ + 2048); \
    buf[3] = *(const bf16x8*)(L_ + 3072); }while(0)

#define RD_B(buf, S, h, kc) do{ \
    const unsigned short* L_ = lds + BBASE(S) + (h)*4096 + (bB ^ ((kc)?32:0)); \
    buf[0] = *(const bf16x8*)(L_); \
    buf[1] = *(const bf16x8*)(L_ + 1024); \
    buf[2] = *(const bf16x8*)(L_ + 2048); \
    buf[3] = *(const bf16x8*)(L_ + 3072); }while(0)

  // one GL16 round = 512 threads x 16B = 64 rows; linear LDS dest.
#define STG(p, DB, OFF) GL16((p) + (OFF), lds + (DB) + wid*512)

  // No setprio / no sched fences: compiler interleaves freely.
#define MMX(AF, BF, NB) do{ \
    _Pragma("unroll") for (int q=0;q<4;q++) \
      _Pragma("unroll") for (int nn=0;nn<4;nn++) \
        acc[q][(NB)+nn] = __builtin_amdgcn_mfma_f32_16x16x32_bf16( \
            AF[q], BF[nn], acc[q][(NB)+nn], 0, 0, 0); }while(0)

#define LGKM0 asm volatile("s_waitcnt lgkmcnt(0)" ::: "memory")
#define BAR  __builtin_amdgcn_s_barrier()
#define VM0  asm volatile("s_waitcnt vmcnt(0)" ::: "memory")
#define VNOP do{}while(0)

  // One K-tile: stage next tile early; body is compiler-scheduled; one
  // lgkmcnt(0)+vmcnt(0)+barrier at the end.
#define TILE(S, OB1, SP, V4) do{ \
    if (SP){ \
      STG(pA0, ABASE((S)^1) + 0,     OB1); \
      STG(pA1, ABASE((S)^1) + 4096,  OB1); \
      STG(pA2, ABASE((S)^1) + 8192,  OB1); \
      STG(pA3, ABASE((S)^1) + 12288, OB1); \
      STG(pB0, BBASE((S)^1) + 0,     OB1); \
      STG(pB1, BBASE((S)^1) + 4096,  OB1); \
      STG(pB2, BBASE((S)^1) + 8192,  OB1); \
      STG(pB3, BBASE((S)^1) + 12288, OB1); } \
    RD_A(a0, S, 0); RD_B(bP, S, 0, 0); RD_B(bQ, S, 1, 0); \
    MMX(a0, bP, 0); \
    RD_A(a1, S, 1); RD_B(bP, S, 1, 1); \
    MMX(a0, bQ, 4); \
    RD_B(bQ, S, 0, 1); \
    MMX(a1, bP, 4); \
    MMX(a1, bQ, 0); \
    LGKM0; V4; BAR; \
    asm volatile("" ::: "memory"); \
  }while(0)

  int nk = K >> 6;                          // 24 K-tiles
  // ---- prologue: stage tile 0 -> slot 0; publish ----
  STG(pA0, ABASE(0)+0, 0);     STG(pA1, ABASE(0)+4096, 0);
  STG(pA2, ABASE(0)+8192, 0);  STG(pA3, ABASE(0)+12288, 0);
  STG(pB0, BBASE(0)+0, 0);     STG(pB1, BBASE(0)+4096, 0);
  STG(pB2, BBASE(0)+8192, 0);  STG(pB3, BBASE(0)+12288, 0);
  VM0; BAR;
  asm volatile("" ::: "memory");

  for (int tt = 0; tt < (nk-2)/2; ++tt){
    TILE(0,  64, 1, VM0);                   // T even: stages T+1 -> slot 1
    TILE(1, 128, 1, VM0);                   // T odd : stages T+2 -> slot 0
    pA0 += 128; pA1 += 128; pA2 += 128; pA3 += 128;
    pB0 += 128; pB1 += 128; pB2 += 128; pB3 += 128;
  }
  TILE(0, 64, 1, VM0);                      // T=nk-2: stages nk-1 -> slot 1
  TILE(1, 0, 0, VNOP);                      // T=nk-1: no staging

#undef TILE
#undef RD_A
#undef RD_B
#undef STG
#undef MMX

  // ---- epilogue: C/D layout col=lane&15, row=(lane>>4)*4+j ----
  int colb = bcol + wc*128 + fr;
  float bv[8];
  #pragma unroll
  for (int n=0;n<8;n++) bv[n] = bias[colb + n*16];
  int r0 = brow + wr*64 + (lane>>4)*4;
  #pragma unroll
  for (int q=0;q<4;q++){
    #pragma unroll
    for (int j=0;j<4;j++){
      int r = r0 + q*16 + j;
      #pragma unroll
      for (int n=0;n<8;n++){
        float x = acc[q][n][j] + bv[n];
        x = x / (1.0f + expf(-x));
        C[(size_t)r*N + colb + n*16] = f2bf(x);
      }
    }
  }
}

// ---------------------------------------------------------------------------
// bf16 MFMA GEMM (m97 structure, 128x128): used for GEMM2.
template<bool SILU, bool OUT_BF16>
__global__ __launch_bounds__(256) void gemm_mfma_kernel(
  const unsigned short* __restrict__ A, const unsigned short* __restrict__ Bt,
  const float* __restrict__ bias, void* __restrict__ C,
  int M, int N, int K)
{
  __shared__ unsigned short As[128*32];
  __shared__ unsigned short Bs[128*32];
  int nbx = N >> 7;
  int bx = blockIdx.x % nbx;
  int by = blockIdx.x / nbx;
  int tid  = threadIdx.x;
  int lane = tid & 63;
  int wid  = tid >> 6;
  int wr = wid >> 1, wc = wid & 1;
  const int brow = by*128, bcol = bx*128;

  int g_r = lane >> 2;
  int g_k = (lane & 3) * 8;
  const unsigned short* Ag0 = A  + (size_t)(brow + wid*32 + g_r)*K + g_k;
  const unsigned short* Ag1 = Ag0 + (size_t)16*K;
  const unsigned short* Bg0 = Bt + (size_t)(bcol + wid*32 + g_r)*K + g_k;
  const unsigned short* Bg1 = Bg0 + (size_t)16*K;
  unsigned short* lA0 = &As[(wid*32 +  0)*32];
  unsigned short* lA1 = &As[(wid*32 + 16)*32];
  unsigned short* lB0 = &Bs[(wid*32 +  0)*32];
  unsigned short* lB1 = &Bs[(wid*32 + 16)*32];

  f32x4 acc[4][4];
  #pragma unroll
  for (int i=0;i<4;i++)
    #pragma unroll
    for (int j=0;j<4;j++) acc[i][j] = (f32x4){0.f,0.f,0.f,0.f};

  int fr = lane & 15;
  int fk = (lane >> 4) * 8;

  for (int kt = 0; kt < K; kt += 32){
    GL16(Ag0 + kt, lA0);
    GL16(Ag1 + kt, lA1);
    GL16(Bg0 + kt, lB0);
    GL16(Bg1 + kt, lB1);
    __syncthreads();
    bf16x8 af[4], bfr[4];
    #pragma unroll
    for (int i=0;i<4;i++){
      af[i]  = *(const bf16x8*)&As[(wr*64 + i*16 + fr)*32 + fk];
      bfr[i] = *(const bf16x8*)&Bs[(wc*64 + i*16 + fr)*32 + fk];
    }
    #pragma unroll
    for (int mi=0;mi<4;mi++)
      #pragma unroll
      for (int ni=0;ni<4;ni++)
        acc[mi][ni] = __builtin_amdgcn_mfma_f32_16x16x32_bf16(af[mi], bfr[ni], acc[mi][ni], 0, 0, 0);
    __syncthreads();
  }

  int col0 = bcol + wc*64 + (lane & 15);
  int row0 = brow + wr*64 + (lane >> 4)*4;
  #pragma unroll
  for (int mi=0;mi<4;mi++){
    #pragma unroll
    for (int j=0;j<4;j++){
      int r = row0 + mi*16 + j;
      #pragma unroll
      for (int ni=0;ni<4;ni++){
        int c = col0 + ni*16;
        float x = acc[mi][ni][j] + bias[c];
        if (SILU) x = x / (1.0f + expf(-x));
        if (OUT_BF16) ((unsigned short*)C)[(size_t)r*N + c] = f2bf(x);
        else          ((float*)C)[(size_t)r*N + c] = x;
      }
    }
  }
}

// ---------------------------------------------------------------------------
// Parallel merge metadata: one block of 512 threads per batch (thread = position).
__global__ __launch_bounds__(512) void merge_meta_kernel(
  const void* __restrict__ maskp, const int* __restrict__ gid,
  const int* __restrict__ flag,
  int* __restrict__ src, int* __restrict__ count)
{
  int b = blockIdx.x;
  int i = threadIdx.x;
  int lane = i & 63, w = i >> 6;
  __shared__ int sg[Ll_];
  __shared__ int fv[8];
  __shared__ int wt[8];
  int f = *flag;
  int mv;
  if (f==0)      mv = ((const int*)maskp)[b*Ll_+i];
  else if (f==1) mv = ((const unsigned char*)maskp)[b*Ll_+i];
  else           mv = (((const float*)maskp)[b*Ll_+i] != 0.0f);
  bool m = (mv != 0);
  int g = gid[b*Ll_+i];
  sg[i] = g;
  unsigned long long W = __ballot(m);
  if (lane==0) fv[w] = W ? (w*64 + __builtin_ctzll(W)) : -1;
  __syncthreads();
  unsigned long long rem = (lane==63) ? 0ull : (W >> (lane+1));
  int nxtpos = -1;
  if (rem) nxtpos = w*64 + lane + 1 + __builtin_ctzll(rem);
  else {
    #pragma unroll
    for (int k=0;k<8;k++)
      if (nxtpos < 0 && k > w && fv[k] >= 0) nxtpos = fv[k];
  }
  int nxt = (nxtpos >= 0) ? sg[nxtpos] : -1;
  bool sep = m && (nxt >= 0) && (nxt != g);
  int ci = (m?1:0) + (sep?1:0);
  int v = ci;
  #pragma unroll
  for (int off=1; off<64; off<<=1){
    int u = __shfl_up(v, off);
    if (lane >= off) v += u;
  }
  if (lane==63) wt[w] = v;
  __syncthreads();
  int woff = 0;
  #pragma unroll
  for (int k=0;k<8;k++) if (k < w) woff += wt[k];
  int e = woff + v - ci;
  int* sb = src + b*Mm_;
  if (m){
    sb[e] = 2*i;
    if (sep) sb[e+1] = 2*i+1;
  }
  if (i==0){
    int tot=0;
    #pragma unroll
    for (int k=0;k<8;k++) tot += wt[k];
    count[b] = tot;
  }
}

// ---------------------------------------------------------------------------
// Final output: right-aligned pieces + pos_emb, zeros elsewhere, plus mask plane.
__global__ __launch_bounds__(256) void output_kernel(
  const float* __restrict__ ev, const float* __restrict__ pos_emb,
  const float* __restrict__ sep_token,
  const int* __restrict__ src, const int* __restrict__ count,
  float* __restrict__ out)
{
  int tid  = threadIdx.x;
  int tpos = blockIdx.x*4 + (tid>>6);
  int lane = tid & 63;
  int b = tpos >> 10;
  int t = tpos & 1023;
  int cnt = count[b];
  int start = Mm_ - cnt;
  float4 val = make_float4(0.f,0.f,0.f,0.f);
  float maskv = 0.f;
  if (t >= start){
    maskv = 1.f;
    int slot = src[b*Mm_ + (t - start)];
    const float* sv = (slot & 1) ? sep_token
                                 : ev + (size_t)(b*Ll_ + (slot>>1))*Hh;
    float4 x = *(const float4*)(sv + lane*4);
    float4 p = *(const float4*)(pos_emb + (size_t)t*Hh + lane*4);
    val = make_float4(x.x+p.x, x.y+p.y, x.z+p.z, x.w+p.w);
  }
  *(float4*)(out + (size_t)tpos*Hh + lane*4) = val;
  if (lane==0) out[(size_t)Bb_*Mm_*Hh + tpos] = maskv;
}

// ---------------------------------------------------------------------------
extern "C" void kernel_launch(void* const* d_in, const int* in_sizes, int n_in,
                              void* d_out, int out_size, void* d_ws, size_t ws_size,
                              hipStream_t stream) {
  const int* tok    = (const int*)d_in[0];
  const int* post   = (const int*)d_in[1];
  const int* auth   = (const int*)d_in[2];
  const int* act    = (const int*)d_in[3];
  const int* tg     = (const int*)d_in[4];
  const int* gid    = (const int*)d_in[5];
  const void* maskp =             d_in[6];
  const float* token_emb = (const float*)d_in[7];
  const float* time_emb  = (const float*)d_in[8];
  const float* group_emb = (const float*)d_in[9];
  const float* pos_emb   = (const float*)d_in[10];
  const float* sep_token = (const float*)d_in[11];
  const float* ln_g = (const float*)d_in[12];
  const float* ln_b = (const float*)d_in[13];
  const float* W1   = (const float*)d_in[14];
  const float* b1   = (const float*)d_in[15];
  const float* W2   = (const float*)d_in[16];
  const float* b2   = (const float*)d_in[17];

  char* ws = (char*)d_ws;
  size_t off = 0;
  int* flag = (int*)ws;                                  off += 256;
  unsigned short* xn  = (unsigned short*)(ws + off);     off += (size_t)BL_*SIXH*2;
  unsigned short* h1  = (unsigned short*)(ws + off);     off += (size_t)BL_*N1_*2;
  float*          ev  = (float*)(ws + off);              off += (size_t)BL_*N2_*4;
  unsigned short* w1t = (unsigned short*)(ws + off);     off += (size_t)K1_*N1_*2;
  unsigned short* w2t = (unsigned short*)(ws + off);     off += (size_t)K2_*N2_*2;
  int*            src = (int*)(ws + off);                off += (size_t)Bb_*Mm_*4;
  int*            cnt = (int*)(ws + off);                off += 256;

  detect_mask_kernel<<<1,256,0,stream>>>((const unsigned int*)maskp, flag);
  transpose_conv_kernel<<<(K1_/32)*(N1_/32),256,0,stream>>>(W1, w1t, K1_, N1_);
  transpose_conv_kernel<<<(K2_/32)*(N2_/32),256,0,stream>>>(W2, w2t, K2_, N2_);
  gather_ln_kernel<<<BL_,256,0,stream>>>(tok,post,auth,act,tg,gid,
                                         token_emb,time_emb,group_emb,
                                         ln_g,ln_b,xn);
  gemm1_cs_kernel<<<(BL_/256)*(N1_/256),512,0,stream>>>(
      xn, w1t, b1, h1, BL_, N1_, K1_);
  gemm_mfma_kernel<false,false><<<(BL_/128)*(N2_/128),256,0,stream>>>(
      h1, w2t, b2, (void*)ev, BL_, N2_, K2_);
  merge_meta_kernel<<<Bb_,512,0,stream>>>(maskp, gid, flag, src, cnt);
  output_kernel<<<(Bb_*Mm_)/4,256,0,stream>>>(ev, pos_emb, sep_token, src, cnt, (float*)d_out);
}